// Round 1
// baseline (6349.984 us; speedup 1.0000x reference)
//
#include <hip/hip_runtime.h>
#include <hip/hip_bf16.h>
#include <hip/hip_cooperative_groups.h>

namespace cg = cooperative_groups;

typedef __hip_bfloat16 bf16;
typedef unsigned short u16;
typedef unsigned int u32;
typedef __attribute__((ext_vector_type(8))) short bf16x8;
typedef __attribute__((ext_vector_type(4))) float f32x4;

// Problem constants
#define BATCH 256
#define TLEN 100
#define HDIM 1024
#define G4 4096
#define HSTRIDE (BATCH * HDIM)          // elements of one h slot
#define OUT_HT (BATCH * TLEN * HDIM)    // float offset of c4 section in d_out

// Workspace layout (byte offsets). Total ~66.8 MB.
#define WS_W0 0u          // bf16 [4096][1088]
#define WS_W1 8912896u    // bf16 [4096][2048]
#define WS_W2 25690112u
#define WS_W3 42467328u
#define WS_BIAS 59244544u // f32  [4][4096]  (bih+bhh)
#define WS_XT 59310080u   // bf16 [100][256][64]
#define WS_H 62586880u    // bf16 [4][2][256][1024] ring

__device__ __forceinline__ float sigm(float x) { return 1.0f / (1.0f + __expf(-x)); }
__device__ __forceinline__ float tanh_(float x) { return 2.0f / (1.0f + __expf(-2.0f * x)) - 1.0f; }

__device__ __forceinline__ void gl_lds16(const void* g, void* l) {
  __builtin_amdgcn_global_load_lds((const __attribute__((address_space(1))) u32*)g,
                                   (__attribute__((address_space(3))) u32*)l, 16, 0, 0);
}

// ---------- setup kernels ----------

// dst[row][k] = bf16( k<din ? Wih[row][k] : Whh[row][k-din] ), row-major [4096][K]
__global__ void pack_w(const float* __restrict__ wih, const float* __restrict__ whh,
                       bf16* __restrict__ dst, int K, int din) {
  int i = blockIdx.x * 256 + threadIdx.x;
  int total4 = (G4 * K) >> 2;
  if (i >= total4) return;
  int e = i << 2;
  int row = e / K;
  int k = e - row * K;
#pragma unroll
  for (int j = 0; j < 4; ++j) {
    int kk = k + j;
    float v = (kk < din) ? wih[row * din + kk] : whh[row * HDIM + (kk - din)];
    dst[e + j] = __float2bfloat16(v);
  }
}

__global__ void pack_bias(const float* __restrict__ a, const float* __restrict__ b,
                          float* __restrict__ dst) {
  int i = blockIdx.x * 256 + threadIdx.x;
  if (i < G4) dst[i] = a[i] + b[i];
}

// xT[t][b][k] = bf16(x[b][t][k])
__global__ void pack_x(const float* __restrict__ x, bf16* __restrict__ xT) {
  int i = blockIdx.x * 256 + threadIdx.x;
  if (i >= TLEN * BATCH * 64) return;
  int k = i & 63;
  int b = (i >> 6) & 255;
  int t = i >> 14;
  xT[i] = __float2bfloat16(x[(b * TLEN + t) * 64 + k]);
}

// ---------- main persistent pipelined kernel ----------
// grid = 256 WGs x 512 threads. WG wg: layer = wg>>6; sub = wg&63;
// b-tile = (sub>>5)*128 (2 tiles), h-tile = (sub&31)*32 (32 tiles).
// Stage s: layer computes timestep t = s - layer (wavefront pipeline), grid.sync per stage.

__global__ void __launch_bounds__(512, 2)
lstm_main(const bf16* __restrict__ Wall, const float* __restrict__ biasc,
          const bf16* __restrict__ xT, bf16* __restrict__ hbuf,
          float* __restrict__ out) {
  // LDS: A/B staging (double buffered, 64B rows -> 128B/row) + gate exchange buffer
  __shared__ u16 As[2][128 * 64];
  __shared__ u16 Bs[2][128 * 64];
  __shared__ float Gs[128 * 132];  // padded stride 132 floats

  const int tid = threadIdx.x;
  const int lane = tid & 63;
  const int wave = tid >> 6;
  const int wg = blockIdx.x;
  const int layer = wg >> 6;
  const int sub = wg & 63;
  const int b0 = (sub >> 5) * 128;
  const int h0 = (sub & 31) * 32;

  const int K = (layer == 0) ? 1088 : 2048;
  const int NC = K >> 6;  // 17 or 32 chunks of 64
  const bf16* Wl = Wall + ((layer == 0) ? 0 : (4456448 + (size_t)(layer - 1) * 8388608));

  // bias registers for this thread's owned column
  const int nn = tid & 31;
  float bias_r[4];
#pragma unroll
  for (int g = 0; g < 4; ++g) bias_r[g] = biasc[layer * G4 + g * HDIM + h0 + nn];

  // cell state: rows r0..r0+7 at column h0+nn, fp32 in registers for the whole sequence
  const int r0 = (tid >> 5) * 8;
  float cst[8];
#pragma unroll
  for (int k = 0; k < 8; ++k) cst[k] = 0.0f;

  // staging geometry: each wave issues 2 A-loads + 2 B-loads per chunk (8 rows x 128B each)
  const int srow = lane >> 3;                         // row within an 8-row issue group
  const int sk = (((lane & 7) ^ srow) << 4) >> 1;     // pre-swizzled element col in chunk
  int arow[2], wrow[2];
#pragma unroll
  for (int q = 0; q < 2; ++q) {
    int j = (wave * 2 + q) * 8 + srow;                // 0..127
    arow[q] = b0 + j;                                 // batch row for A
    wrow[q] = ((j >> 5) << 10) + h0 + (j & 31);       // weight row (gate-major)
  }

  // compute sub-tile for this wave: 32 rows x 64 cols of the 128x128 WG tile
  const int mb = (wave & 3) * 32;
  const int nbase = (wave >> 2) * 64;
  const int lrow = lane & 15;
  const int lcb0 = (lane >> 4) << 4;   // 0,16,32,48 byte col
  const int lswz = (lane & 7) << 4;    // XOR swizzle term (row&7 == lane&7 here)

  cg::grid_group grid = cg::this_grid();

  for (int s = 0; s < TLEN + 3; ++s) {
    const int t = s - layer;
    if (t >= 0 && t < TLEN) {
      const bf16* hin = hbuf + ((layer == 0) ? 0 : ((size_t)((layer - 1) * 2 + (t & 1)) * HSTRIDE));
      const bf16* hprev = hbuf + (size_t)(layer * 2 + ((t + 1) & 1)) * HSTRIDE;
      const bf16* xrow = xT + (size_t)t * (BATCH * 64);

      f32x4 acc[2][4];
#pragma unroll
      for (int mt = 0; mt < 2; ++mt)
#pragma unroll
        for (int nt = 0; nt < 4; ++nt) acc[mt][nt] = (f32x4)(0.0f);

      auto stage = [&](int c, int buf) {
#pragma unroll
        for (int q = 0; q < 2; ++q) {
          const bf16* src;
          if (layer == 0) {
            src = (c == 0) ? (xrow + arow[q] * 64 + sk)
                           : (hprev + arow[q] * HDIM + (c - 1) * 64 + sk);
          } else {
            src = (c < 16) ? (hin + arow[q] * HDIM + c * 64 + sk)
                           : (hprev + arow[q] * HDIM + (c - 16) * 64 + sk);
          }
          gl_lds16(src, &As[buf][(wave * 2 + q) * 512]);
        }
#pragma unroll
        for (int q = 0; q < 2; ++q) {
          const bf16* src = Wl + (size_t)wrow[q] * K + c * 64 + sk;
          gl_lds16(src, &Bs[buf][(wave * 2 + q) * 512]);
        }
      };

      stage(0, 0);
      __syncthreads();

      for (int c = 0; c < NC; ++c) {
        const int buf = c & 1;
        if (c + 1 < NC) stage(c + 1, buf ^ 1);

#pragma unroll
        for (int ks = 0; ks < 2; ++ks) {
          bf16x8 a[2], b[4];
#pragma unroll
          for (int mt = 0; mt < 2; ++mt) {
            int row = mb + mt * 16 + lrow;
            int off = row * 128 + ((ks * 64 + lcb0) ^ lswz);
            a[mt] = *(const bf16x8*)((const char*)&As[buf][0] + off);
          }
#pragma unroll
          for (int nt = 0; nt < 4; ++nt) {
            int j = nbase + nt * 16 + lrow;
            int off = j * 128 + ((ks * 64 + lcb0) ^ lswz);
            b[nt] = *(const bf16x8*)((const char*)&Bs[buf][0] + off);
          }
#pragma unroll
          for (int mt = 0; mt < 2; ++mt)
#pragma unroll
            for (int nt = 0; nt < 4; ++nt)
              acc[mt][nt] = __builtin_amdgcn_mfma_f32_16x16x32_bf16(a[mt], b[nt], acc[mt][nt], 0, 0, 0);
        }
        __syncthreads();
      }

      // dump gate tiles to LDS (D layout: col=lane&15, row=(lane>>4)*4+r)
#pragma unroll
      for (int mt = 0; mt < 2; ++mt)
#pragma unroll
        for (int nt = 0; nt < 4; ++nt) {
          int row = mb + mt * 16 + (lane >> 4) * 4;
          int col = nbase + nt * 16 + (lane & 15);
#pragma unroll
          for (int r = 0; r < 4; ++r) Gs[(row + r) * 132 + col] = acc[mt][nt][r];
        }
      __syncthreads();

      // LSTM cell update; c stays in registers
      bf16* hout = hbuf + (size_t)(layer * 2 + (t & 1)) * HSTRIDE;
#pragma unroll
      for (int k = 0; k < 8; ++k) {
        int r = r0 + k;
        float gi = Gs[r * 132 + nn] + bias_r[0];
        float gf = Gs[r * 132 + 32 + nn] + bias_r[1];
        float gg = Gs[r * 132 + 64 + nn] + bias_r[2];
        float go = Gs[r * 132 + 96 + nn] + bias_r[3];
        float iv = sigm(gi), fv = sigm(gf), gv = tanh_(gg), ov = sigm(go);
        float cv = fv * cst[k] + iv * gv;
        cst[k] = cv;
        float hv = ov * tanh_(cv);
        hout[(b0 + r) * HDIM + h0 + nn] = __float2bfloat16(hv);
        if (layer == 3) {
          out[((size_t)(b0 + r) * TLEN + t) * HDIM + h0 + nn] = hv;
          if (t == TLEN - 1) out[OUT_HT + (size_t)(b0 + r) * HDIM + h0 + nn] = cv;
        }
      }
    }
    grid.sync();
  }
}

// ---------- host ----------

extern "C" void kernel_launch(void* const* d_in, const int* in_sizes, int n_in,
                              void* d_out, int out_size, void* d_ws, size_t ws_size,
                              hipStream_t stream) {
  const float* x = (const float*)d_in[0];
  const float* Wih[4] = {(const float*)d_in[1], (const float*)d_in[5],
                         (const float*)d_in[9], (const float*)d_in[13]};
  const float* Whh[4] = {(const float*)d_in[2], (const float*)d_in[6],
                         (const float*)d_in[10], (const float*)d_in[14]};
  const float* bih[4] = {(const float*)d_in[3], (const float*)d_in[7],
                         (const float*)d_in[11], (const float*)d_in[15]};
  const float* bhh[4] = {(const float*)d_in[4], (const float*)d_in[8],
                         (const float*)d_in[12], (const float*)d_in[16]};

  char* ws = (char*)d_ws;
  bf16* Wall = (bf16*)(ws + WS_W0);
  float* biasc = (float*)(ws + WS_BIAS);
  bf16* xT = (bf16*)(ws + WS_XT);
  bf16* hbuf = (bf16*)(ws + WS_H);
  float* out = (float*)d_out;

  for (int l = 0; l < 4; ++l) {
    int K = (l == 0) ? 1088 : 2048;
    int din = (l == 0) ? 64 : 1024;
    bf16* dst = Wall + ((l == 0) ? 0 : (4456448 + (size_t)(l - 1) * 8388608));
    int total4 = (4096 * K) >> 2;
    pack_w<<<(total4 + 255) / 256, 256, 0, stream>>>(Wih[l], Whh[l], dst, K, din);
    pack_bias<<<16, 256, 0, stream>>>(bih[l], bhh[l], biasc + l * 4096);
  }
  pack_x<<<(TLEN * BATCH * 64 + 255) / 256, 256, 0, stream>>>(x, xT);
  hipMemsetAsync(hbuf, 0, 4u * 1024u * 1024u, stream);

  void* args[] = {(void*)&Wall, (void*)&biasc, (void*)&xT, (void*)&hbuf, (void*)&out};
  hipLaunchCooperativeKernel((void*)lstm_main, dim3(256), dim3(512), args, 0, stream);
}

// Round 2
// 3555.674 us; speedup vs baseline: 1.7859x; 1.7859x over previous
//
#include <hip/hip_runtime.h>
#include <hip/hip_bf16.h>

typedef __hip_bfloat16 bf16;
typedef unsigned short u16;
typedef unsigned int u32;
typedef __attribute__((ext_vector_type(8))) short bf16x8;
typedef __attribute__((ext_vector_type(4))) float f32x4;

// Problem constants
#define BATCH 256
#define TLEN 100
#define HDIM 1024
#define G4 4096
#define HSTRIDE (BATCH * HDIM)          // elements of one h slot
#define OUT_HT (BATCH * TLEN * HDIM)    // float offset of c4 section in d_out

// Workspace layout (byte offsets). Total ~66.8 MB.
#define WS_W0 0u          // bf16 [4096][1088]
#define WS_W1 8912896u    // bf16 [4096][2048]
#define WS_W2 25690112u
#define WS_W3 42467328u
#define WS_BIAS 59244544u // f32  [4][4096]  (bih+bhh)
#define WS_XT 59310080u   // bf16 [100][256][64]
#define WS_H 62586880u    // bf16 [4][2][256][1024] ring
#define WS_BAR (WS_H + 4194304u)  // u32 arrive @ +0, release @ +128

__device__ __forceinline__ float sigm(float x) { return 1.0f / (1.0f + __expf(-x)); }
__device__ __forceinline__ float tanh_(float x) { return 2.0f / (1.0f + __expf(-2.0f * x)) - 1.0f; }

__device__ __forceinline__ void gl_lds16(const void* g, void* l) {
  __builtin_amdgcn_global_load_lds((const __attribute__((address_space(1))) u32*)g,
                                   (__attribute__((address_space(3))) u32*)l, 16, 0, 0);
}

// Lean sense-free global barrier: monotone release epoch, one ACQ_REL RMW per WG.
// All 256 WGs are co-resident (cooperative launch), so spinning is safe.
__device__ __forceinline__ void gbar(u32* arrive, u32* release, u32 epoch, int tid) {
  __syncthreads();
  if (tid == 0) {
    // ACQ_REL: releases this WG's h-stores to agent scope, acquires others' on exit.
    u32 old = __hip_atomic_fetch_add(arrive, 1u, __ATOMIC_ACQ_REL, __HIP_MEMORY_SCOPE_AGENT);
    if (old == 255u) {
      __hip_atomic_store(arrive, 0u, __ATOMIC_RELAXED, __HIP_MEMORY_SCOPE_AGENT);
      // RELEASE orders the arrive-reset before the epoch publish.
      __hip_atomic_store(release, epoch, __ATOMIC_RELEASE, __HIP_MEMORY_SCOPE_AGENT);
    } else {
      // Relaxed agent-scope polls (no per-poll cache inv); one acquire fence on exit.
      while (__hip_atomic_load(release, __ATOMIC_RELAXED, __HIP_MEMORY_SCOPE_AGENT) < epoch)
        __builtin_amdgcn_s_sleep(2);
      __builtin_amdgcn_fence(__ATOMIC_ACQUIRE, "agent");
    }
  }
  __syncthreads();
}

// ---------- setup kernels ----------

__global__ void pack_w(const float* __restrict__ wih, const float* __restrict__ whh,
                       bf16* __restrict__ dst, int K, int din) {
  int i = blockIdx.x * 256 + threadIdx.x;
  int total4 = (G4 * K) >> 2;
  if (i >= total4) return;
  int e = i << 2;
  int row = e / K;
  int k = e - row * K;
#pragma unroll
  for (int j = 0; j < 4; ++j) {
    int kk = k + j;
    float v = (kk < din) ? wih[row * din + kk] : whh[row * HDIM + (kk - din)];
    dst[e + j] = __float2bfloat16(v);
  }
}

__global__ void pack_bias(const float* __restrict__ a, const float* __restrict__ b,
                          float* __restrict__ dst) {
  int i = blockIdx.x * 256 + threadIdx.x;
  if (i < G4) dst[i] = a[i] + b[i];
}

__global__ void pack_x(const float* __restrict__ x, bf16* __restrict__ xT) {
  int i = blockIdx.x * 256 + threadIdx.x;
  if (i >= TLEN * BATCH * 64) return;
  int k = i & 63;
  int b = (i >> 6) & 255;
  int t = i >> 14;
  xT[i] = __float2bfloat16(x[(b * TLEN + t) * 64 + k]);
}

// ---------- main persistent pipelined kernel ----------
// grid = 256 WGs x 512 threads. WG wg: layer = wg>>6; sub = wg&63;
// b-tile = (sub>>5)*128, h-tile = (sub&31)*32. Stage s: layer computes t = s - layer.
// K-loop: 4 LDS buffers, prefetch distance 3, counted vmcnt (T3/T4) — never drains
// in-flight loads at the per-chunk barriers.

__global__ void __launch_bounds__(512, 2)
lstm_main(const bf16* __restrict__ Wall, const float* __restrict__ biasc,
          const bf16* __restrict__ xT, bf16* __restrict__ hbuf,
          float* __restrict__ out, u32* __restrict__ barr) {
  // 128 KB: A staging 4 bufs x 16 KB @ 0, B staging 4 bufs x 16 KB @ 64 KB.
  // Gate-exchange buffer (67.6 KB) aliases the staging region (dead by epilogue).
  __shared__ __align__(16) u16 smem[65536];
  float* Gs = (float*)smem;  // [128][132]

  const int tid = threadIdx.x;
  const int lane = tid & 63;
  const int wave = tid >> 6;
  const int wg = blockIdx.x;
  const int layer = wg >> 6;
  const int sub = wg & 63;
  const int b0 = (sub >> 5) * 128;
  const int h0 = (sub & 31) * 32;

  const int K = (layer == 0) ? 1088 : 2048;
  const int NC = K >> 6;  // 17 or 32 chunks of 64
  const bf16* Wl = Wall + ((layer == 0) ? 0 : (4456448 + (size_t)(layer - 1) * 8388608));

  const int nn = tid & 31;
  float bias_r[4];
#pragma unroll
  for (int g = 0; g < 4; ++g) bias_r[g] = biasc[layer * G4 + g * HDIM + h0 + nn];

  const int r0 = (tid >> 5) * 8;
  float cst[8];
#pragma unroll
  for (int k = 0; k < 8; ++k) cst[k] = 0.0f;

  // staging geometry: each wave issues 2 A-loads + 2 B-loads per chunk
  const int srow = lane >> 3;
  const int sk = (((lane & 7) ^ srow) << 4) >> 1;  // pre-swizzled element col
  int arow[2], wrow[2];
#pragma unroll
  for (int q = 0; q < 2; ++q) {
    int j = (wave * 2 + q) * 8 + srow;
    arow[q] = b0 + j;
    wrow[q] = ((j >> 5) << 10) + h0 + (j & 31);
  }

  const int mb = (wave & 3) * 32;
  const int nbase = (wave >> 2) * 64;
  const int lrow = lane & 15;
  const int lcb0 = (lane >> 4) << 4;
  const int lswz = (lane & 7) << 4;

  u32* bar_arrive = barr;
  u32* bar_release = barr + 32;

  for (int s = 0; s < TLEN + 3; ++s) {
    const int t = s - layer;
    if (t >= 0 && t < TLEN) {
      const bf16* hin = hbuf + ((layer == 0) ? 0 : ((size_t)((layer - 1) * 2 + (t & 1)) * HSTRIDE));
      const bf16* hprev = hbuf + (size_t)(layer * 2 + ((t + 1) & 1)) * HSTRIDE;
      const bf16* xrow = xT + (size_t)t * (BATCH * 64);

      f32x4 acc[2][4];
#pragma unroll
      for (int mt = 0; mt < 2; ++mt)
#pragma unroll
        for (int nt = 0; nt < 4; ++nt) acc[mt][nt] = (f32x4)(0.0f);

      auto stage = [&](int c, int buf) {
#pragma unroll
        for (int q = 0; q < 2; ++q) {
          const bf16* src;
          if (layer == 0) {
            src = (c == 0) ? (xrow + arow[q] * 64 + sk)
                           : (hprev + arow[q] * HDIM + (c - 1) * 64 + sk);
          } else {
            src = (c < 16) ? (hin + arow[q] * HDIM + c * 64 + sk)
                           : (hprev + arow[q] * HDIM + (c - 16) * 64 + sk);
          }
          gl_lds16(src, smem + buf * 8192 + (wave * 2 + q) * 512);
        }
#pragma unroll
        for (int q = 0; q < 2; ++q) {
          const bf16* src = Wl + (size_t)wrow[q] * K + c * 64 + sk;
          gl_lds16(src, smem + 32768 + buf * 8192 + (wave * 2 + q) * 512);
        }
      };

      // prologue: fill 3 buffers
      stage(0, 0);
      stage(1, 1);
      stage(2, 2);

      for (int c = 0; c < NC; ++c) {
        const int buf = c & 3;
        if (c + 3 < NC) stage(c + 3, (c + 3) & 3);

        // wait until THIS chunk's 4 loads are complete; keep younger prefetches in flight
        const int rem = NC - 1 - c;
        if (rem >= 3)      asm volatile("s_waitcnt vmcnt(12)" ::: "memory");
        else if (rem == 2) asm volatile("s_waitcnt vmcnt(8)" ::: "memory");
        else if (rem == 1) asm volatile("s_waitcnt vmcnt(4)" ::: "memory");
        else               asm volatile("s_waitcnt vmcnt(0)" ::: "memory");
        __builtin_amdgcn_s_barrier();  // all waves' chunk-c loads landed

        const char* Abuf = (const char*)smem + buf * 16384;
        const char* Bbuf = (const char*)smem + 65536 + buf * 16384;
        bf16x8 a[2][2], b[2][4];
#pragma unroll
        for (int ks = 0; ks < 2; ++ks) {
#pragma unroll
          for (int mt = 0; mt < 2; ++mt) {
            int row = mb + mt * 16 + lrow;
            a[ks][mt] = *(const bf16x8*)(Abuf + row * 128 + ((ks * 64 + lcb0) ^ lswz));
          }
#pragma unroll
          for (int nt = 0; nt < 4; ++nt) {
            int j = nbase + nt * 16 + lrow;
            b[ks][nt] = *(const bf16x8*)(Bbuf + j * 128 + ((ks * 64 + lcb0) ^ lswz));
          }
        }
        __builtin_amdgcn_s_barrier();  // reads done -> next iter may overwrite this buf

#pragma unroll
        for (int ks = 0; ks < 2; ++ks)
#pragma unroll
          for (int mt = 0; mt < 2; ++mt)
#pragma unroll
            for (int nt = 0; nt < 4; ++nt)
              acc[mt][nt] = __builtin_amdgcn_mfma_f32_16x16x32_bf16(a[ks][mt], b[ks][nt], acc[mt][nt], 0, 0, 0);
      }

      __syncthreads();  // K-loop fully done (incl. MFMA reads) before Gs alias-write

      // dump gate tiles to LDS (D layout: col=lane&15, row=(lane>>4)*4+r)
#pragma unroll
      for (int mt = 0; mt < 2; ++mt)
#pragma unroll
        for (int nt = 0; nt < 4; ++nt) {
          int row = mb + mt * 16 + (lane >> 4) * 4;
          int col = nbase + nt * 16 + (lane & 15);
#pragma unroll
          for (int r = 0; r < 4; ++r) Gs[(row + r) * 132 + col] = acc[mt][nt][r];
        }
      __syncthreads();

      // LSTM cell update; c stays in registers
      bf16* hout = hbuf + (size_t)(layer * 2 + (t & 1)) * HSTRIDE;
#pragma unroll
      for (int k = 0; k < 8; ++k) {
        int r = r0 + k;
        float gi = Gs[r * 132 + nn] + bias_r[0];
        float gf = Gs[r * 132 + 32 + nn] + bias_r[1];
        float gg = Gs[r * 132 + 64 + nn] + bias_r[2];
        float go = Gs[r * 132 + 96 + nn] + bias_r[3];
        float iv = sigm(gi), fv = sigm(gf), gv = tanh_(gg), ov = sigm(go);
        float cv = fv * cst[k] + iv * gv;
        cst[k] = cv;
        float hv = ov * tanh_(cv);
        hout[(b0 + r) * HDIM + h0 + nn] = __float2bfloat16(hv);
        if (layer == 3) {
          out[((size_t)(b0 + r) * TLEN + t) * HDIM + h0 + nn] = hv;
          if (t == TLEN - 1) out[OUT_HT + (size_t)(b0 + r) * HDIM + h0 + nn] = cv;
        }
      }
    }
    if (s < TLEN + 2) gbar(bar_arrive, bar_release, (u32)(s + 1), tid);
  }
}

// ---------- host ----------

extern "C" void kernel_launch(void* const* d_in, const int* in_sizes, int n_in,
                              void* d_out, int out_size, void* d_ws, size_t ws_size,
                              hipStream_t stream) {
  const float* x = (const float*)d_in[0];
  const float* Wih[4] = {(const float*)d_in[1], (const float*)d_in[5],
                         (const float*)d_in[9], (const float*)d_in[13]};
  const float* Whh[4] = {(const float*)d_in[2], (const float*)d_in[6],
                         (const float*)d_in[10], (const float*)d_in[14]};
  const float* bih[4] = {(const float*)d_in[3], (const float*)d_in[7],
                         (const float*)d_in[11], (const float*)d_in[15]};
  const float* bhh[4] = {(const float*)d_in[4], (const float*)d_in[8],
                         (const float*)d_in[12], (const float*)d_in[16]};

  char* ws = (char*)d_ws;
  bf16* Wall = (bf16*)(ws + WS_W0);
  float* biasc = (float*)(ws + WS_BIAS);
  bf16* xT = (bf16*)(ws + WS_XT);
  bf16* hbuf = (bf16*)(ws + WS_H);
  u32* barr = (u32*)(ws + WS_BAR);
  float* out = (float*)d_out;

  for (int l = 0; l < 4; ++l) {
    int K = (l == 0) ? 1088 : 2048;
    int din = (l == 0) ? 64 : 1024;
    bf16* dst = Wall + ((l == 0) ? 0 : (4456448 + (size_t)(l - 1) * 8388608));
    int total4 = (4096 * K) >> 2;
    pack_w<<<(total4 + 255) / 256, 256, 0, stream>>>(Wih[l], Whh[l], dst, K, din);
    pack_bias<<<16, 256, 0, stream>>>(bih[l], bhh[l], biasc + l * 4096);
  }
  pack_x<<<(TLEN * BATCH * 64 + 255) / 256, 256, 0, stream>>>(x, xT);
  // zero h ring + barrier state
  hipMemsetAsync(hbuf, 0, 4194304u + 256u, stream);

  void* args[] = {(void*)&Wall, (void*)&biasc, (void*)&xT, (void*)&hbuf, (void*)&out, (void*)&barr};
  hipLaunchCooperativeKernel((void*)lstm_main, dim3(256), dim3(512), args, 0, stream);
}

// Round 3
// 3309.260 us; speedup vs baseline: 1.9189x; 1.0745x over previous
//
#include <hip/hip_runtime.h>
#include <hip/hip_bf16.h>

typedef __hip_bfloat16 bf16;
typedef unsigned short u16;
typedef unsigned int u32;
typedef __attribute__((ext_vector_type(8))) short bf16x8;
typedef __attribute__((ext_vector_type(4))) float f32x4;

// Problem constants
#define BATCH 256
#define TLEN 100
#define HDIM 1024
#define G4 4096
#define OUT_HT (BATCH * TLEN * HDIM)    // float offset of c4 section in d_out

// Workspace layout (byte offsets).
// Wp: pre-tiled weights. layer0: 32 slices x 17 chunks x 16KB = 8912896 B.
//     layers 1-3: 32 slices x 32 chunks x 16KB = 16777216 B each.
#define WS_WP 0u
#define WS_BIAS 59244544u   // f32 [4][4096]
#define WS_XT 59310080u     // bf16 chunk-major [100][256][64], swizzle baked
#define WS_H 62586880u      // bf16 [8 slots][16 chunks][256][64], swizzle baked
#define WS_BAR (WS_H + 4194304u)

__device__ __forceinline__ float sigm(float x) { return 1.0f / (1.0f + __expf(-x)); }
__device__ __forceinline__ float tanh_(float x) { return 2.0f / (1.0f + __expf(-2.0f * x)) - 1.0f; }

__device__ __forceinline__ void gl_lds16(const void* g, void* l) {
  __builtin_amdgcn_global_load_lds((const __attribute__((address_space(1))) u32*)g,
                                   (__attribute__((address_space(3))) u32*)l, 16, 0, 0);
}

// Lean global barrier (proven in R2): monotone release epoch, one ACQ_REL RMW per WG.
__device__ __forceinline__ void gbar(u32* arrive, u32* release, u32 epoch, int tid) {
  __syncthreads();
  if (tid == 0) {
    u32 old = __hip_atomic_fetch_add(arrive, 1u, __ATOMIC_ACQ_REL, __HIP_MEMORY_SCOPE_AGENT);
    if (old == 255u) {
      __hip_atomic_store(arrive, 0u, __ATOMIC_RELAXED, __HIP_MEMORY_SCOPE_AGENT);
      __hip_atomic_store(release, epoch, __ATOMIC_RELEASE, __HIP_MEMORY_SCOPE_AGENT);
    } else {
      while (__hip_atomic_load(release, __ATOMIC_RELAXED, __HIP_MEMORY_SCOPE_AGENT) < epoch)
        __builtin_amdgcn_s_sleep(2);
      __builtin_amdgcn_fence(__ATOMIC_ACQUIRE, "agent");
    }
  }
  __syncthreads();
}

// ---------- setup kernels ----------

// Pre-tile weights into per-(slice j, chunk c) 16KB LDS images, XOR-swizzle baked.
// dst element (j, c, r, k6): grow = (r>>5)*1024 + j*32 + (r&31), k = c*64 + k6
// dst u16 idx = (j*NC + c)*8192 + r*64 + (k6 ^ ((r&7)<<3))
__global__ void pack_w(const float* __restrict__ wih, const float* __restrict__ whh,
                       bf16* __restrict__ dst, int NC, int din) {
  int i = blockIdx.x * 256 + threadIdx.x;
  if (i >= 32 * NC * 128 * 64) return;
  int k6 = i & 63;
  int r = (i >> 6) & 127;
  int jc = i >> 13;
  int c = jc % NC;
  int j = jc / NC;
  int grow = ((r >> 5) << 10) + j * 32 + (r & 31);
  int k = c * 64 + k6;
  float v = (k < din) ? wih[grow * din + k] : whh[(grow << 10) + (k - din)];
  dst[(jc << 13) + (r << 6) + (k6 ^ ((r & 7) << 3))] = __float2bfloat16(v);
}

__global__ void pack_bias(const float* __restrict__ a, const float* __restrict__ b,
                          float* __restrict__ dst) {
  int i = blockIdx.x * 256 + threadIdx.x;
  if (i < G4) dst[i] = a[i] + b[i];
}

// xT chunk image: [t][b][64] bf16 with baked swizzle (k ^ ((b&7)<<3))
__global__ void pack_x(const float* __restrict__ x, bf16* __restrict__ xT) {
  int i = blockIdx.x * 256 + threadIdx.x;
  if (i >= TLEN * BATCH * 64) return;
  int k = i & 63;
  int b = (i >> 6) & 255;
  int t = i >> 14;
  xT[(t << 14) + (b << 6) + (k ^ ((b & 7) << 3))] = __float2bfloat16(x[(b * TLEN + t) * 64 + k]);
}

// ---------- main persistent pipelined kernel ----------
// 256 WGs x 512 threads. layer = wg>>6; sub = wg&63; b0 = (sub>>5)*128; h0 = (sub&31)*32.
// All staging reads are contiguous 16KB/chunk. A ring: 4 bufs, issue depth 2.
// B ring: 5 bufs, depth 3. One s_barrier per chunk; counted vmcnt 10/8/4/0.

__global__ void __launch_bounds__(512, 2)
lstm_main(const u16* __restrict__ Wp, const float* __restrict__ biasc,
          const u16* __restrict__ xT, u16* __restrict__ hbuf,
          float* __restrict__ out, u32* __restrict__ barr) {
  // A bufs: u16 [4][8192] @ 0 (64KB). B bufs: u16 [5][8192] @ 32768 (80KB). Total 144KB.
  __shared__ __align__(16) u16 smem[73728];
  float* Gs = (float*)smem;  // [128][132] aliases (dead during epilogue)

  const int tid = threadIdx.x;
  const int lane = tid & 63;
  const int wave = tid >> 6;
  const int wg = blockIdx.x;
  const int layer = wg >> 6;
  const int sub = wg & 63;
  const int b0 = (sub >> 5) * 128;
  const int h0 = (sub & 31) * 32;

  const int NC = (layer == 0) ? 17 : 32;
  const int T0 = (layer == 0) ? 1 : 16;
  // weight slice base (u16 units)
  const u16* Wsl = Wp + ((layer == 0) ? 0u : (4456448u + (u32)(layer - 1) * 8388608u))
                 + (u32)(sub & 31) * (u32)NC * 8192u;

  const int nn = tid & 31;
  float bias_r[4];
#pragma unroll
  for (int g = 0; g < 4; ++g) bias_r[g] = biasc[layer * G4 + g * HDIM + h0 + nn];

  const int r0 = (tid >> 5) * 8;
  float cst[8];
#pragma unroll
  for (int k = 0; k < 8; ++k) cst[k] = 0.0f;

  // staging: per wave 2 ops x 1KB contiguous; op q offset (wave*2+q)*512 u16 + lane*8 u16
  const int opu0 = (wave * 2) * 512 + lane * 8;   // u16 units, op 0
  const int opu1 = opu0 + 512;                    // op 1

  // compute sub-tile: wave covers rows mb..mb+31, cols nbase..nbase+63 of 128x128
  const int mb = (wave & 3) * 32;
  const int nbase = (wave >> 2) * 64;
  const int lrow = lane & 15;
  const int lcb0 = (lane >> 4) << 4;
  const int lswz = (lane & 7) << 4;

  u32* bar_arrive = barr;
  u32* bar_release = barr + 32;

  for (int s = 0; s < TLEN + 3; ++s) {
    const int t = s - layer;
    if (t >= 0 && t < TLEN) {
      // A chunk-major bases (u16): chunk block = 16384 u16; this WG's 16KB at +b0*64
      const u16* aBase0 = ((layer == 0) ? (xT + (u32)t * 16384u)
                                        : (hbuf + (u32)((layer - 1) * 2 + (t & 1)) * 262144u))
                        + b0 * 64;
      const u16* aBase1 = hbuf + (u32)(layer * 2 + ((t + 1) & 1)) * 262144u + b0 * 64;

      f32x4 acc[2][4];
#pragma unroll
      for (int mt = 0; mt < 2; ++mt)
#pragma unroll
        for (int nt = 0; nt < 4; ++nt) acc[mt][nt] = (f32x4)(0.0f);

      auto issueA = [&](int c, int slot) {
        const u16* src = (c < T0) ? (aBase0 + c * 16384) : (aBase1 + (c - T0) * 16384);
        gl_lds16(src + opu0, smem + slot * 8192 + (wave * 2) * 512);
        gl_lds16(src + opu1, smem + slot * 8192 + (wave * 2 + 1) * 512);
      };
      auto issueB = [&](int c, int slot) {
        const u16* src = Wsl + c * 8192;
        gl_lds16(src + opu0, smem + 32768 + slot * 8192 + (wave * 2) * 512);
        gl_lds16(src + opu1, smem + 32768 + slot * 8192 + (wave * 2 + 1) * 512);
      };

      // prologue: order B0,A0,B1,A1,B2 (matches steady-state vmcnt accounting)
      issueB(0, 0);
      issueA(0, 0);
      issueB(1, 1);
      issueA(1, 1);
      issueB(2, 2);

      int iar = 0, ibr = 0, iaw = 2, ibw = 3;
      for (int c = 0; c < NC; ++c) {
        const int rem = NC - 1 - c;
        if (rem >= 2) issueA(c + 2, iaw);
        if (rem >= 3) issueB(c + 3, ibw);

        // retire this chunk's A+B (oldest 4 ops); keep younger prefetches in flight
        if (rem >= 3)      asm volatile("s_waitcnt vmcnt(10)" ::: "memory");
        else if (rem == 2) asm volatile("s_waitcnt vmcnt(8)" ::: "memory");
        else if (rem == 1) asm volatile("s_waitcnt vmcnt(4)" ::: "memory");
        else               asm volatile("s_waitcnt vmcnt(0)" ::: "memory");
        __builtin_amdgcn_s_barrier();

        const char* Abuf = (const char*)smem + iar * 16384;
        const char* Bbuf = (const char*)smem + 65536 + ibr * 16384;
        bf16x8 a[2][2], b[2][4];
#pragma unroll
        for (int ks = 0; ks < 2; ++ks) {
#pragma unroll
          for (int mt = 0; mt < 2; ++mt) {
            int row = mb + mt * 16 + lrow;
            a[ks][mt] = *(const bf16x8*)(Abuf + row * 128 + ((ks * 64 + lcb0) ^ lswz));
          }
#pragma unroll
          for (int nt = 0; nt < 4; ++nt) {
            int j = nbase + nt * 16 + lrow;
            b[ks][nt] = *(const bf16x8*)(Bbuf + j * 128 + ((ks * 64 + lcb0) ^ lswz));
          }
        }
#pragma unroll
        for (int ks = 0; ks < 2; ++ks)
#pragma unroll
          for (int mt = 0; mt < 2; ++mt)
#pragma unroll
            for (int nt = 0; nt < 4; ++nt)
              acc[mt][nt] = __builtin_amdgcn_mfma_f32_16x16x32_bf16(a[ks][mt], b[ks][nt], acc[mt][nt], 0, 0, 0);

        iar = (iar + 1) & 3;
        iaw = (iaw + 1) & 3;
        ibr = (ibr == 4) ? 0 : ibr + 1;
        ibw = (ibw == 4) ? 0 : ibw + 1;
      }

      __syncthreads();  // K-loop reads done before Gs alias-write

      // dump gate tiles to LDS (D layout: col=lane&15, row=(lane>>4)*4+r)
#pragma unroll
      for (int mt = 0; mt < 2; ++mt)
#pragma unroll
        for (int nt = 0; nt < 4; ++nt) {
          int row = mb + mt * 16 + (lane >> 4) * 4;
          int col = nbase + nt * 16 + (lane & 15);
#pragma unroll
          for (int r = 0; r < 4; ++r) Gs[(row + r) * 132 + col] = acc[mt][nt][r];
        }
      __syncthreads();

      // LSTM cell update; c stays in registers. h stored chunk-major, swizzle baked.
      u16* outSlot = hbuf + (u32)(layer * 2 + (t & 1)) * 262144u;
      const int hcol = h0 + nn;
      const int j2 = hcol >> 6;
      const int colin = hcol & 63;
#pragma unroll
      for (int k = 0; k < 8; ++k) {
        int r = r0 + k;
        float gi = Gs[r * 132 + nn] + bias_r[0];
        float gf = Gs[r * 132 + 32 + nn] + bias_r[1];
        float gg = Gs[r * 132 + 64 + nn] + bias_r[2];
        float go = Gs[r * 132 + 96 + nn] + bias_r[3];
        float iv = sigm(gi), fv = sigm(gf), gv = tanh_(gg), ov = sigm(go);
        float cv = fv * cst[k] + iv * gv;
        cst[k] = cv;
        float hv = ov * tanh_(cv);
        int b = b0 + r;
        bf16 hb = __float2bfloat16(hv);
        outSlot[j2 * 16384 + b * 64 + (colin ^ ((b & 7) << 3))] = *(u16*)&hb;
        if (layer == 3) {
          out[((size_t)b * TLEN + t) * HDIM + hcol] = hv;
          if (t == TLEN - 1) out[OUT_HT + (size_t)b * HDIM + hcol] = cv;
        }
      }
    }
    if (s < TLEN + 2) gbar(bar_arrive, bar_release, (u32)(s + 1), tid);
  }
}

// ---------- host ----------

extern "C" void kernel_launch(void* const* d_in, const int* in_sizes, int n_in,
                              void* d_out, int out_size, void* d_ws, size_t ws_size,
                              hipStream_t stream) {
  const float* x = (const float*)d_in[0];
  const float* Wih[4] = {(const float*)d_in[1], (const float*)d_in[5],
                         (const float*)d_in[9], (const float*)d_in[13]};
  const float* Whh[4] = {(const float*)d_in[2], (const float*)d_in[6],
                         (const float*)d_in[10], (const float*)d_in[14]};
  const float* bih[4] = {(const float*)d_in[3], (const float*)d_in[7],
                         (const float*)d_in[11], (const float*)d_in[15]};
  const float* bhh[4] = {(const float*)d_in[4], (const float*)d_in[8],
                         (const float*)d_in[12], (const float*)d_in[16]};

  char* ws = (char*)d_ws;
  bf16* Wp = (bf16*)(ws + WS_WP);
  float* biasc = (float*)(ws + WS_BIAS);
  bf16* xT = (bf16*)(ws + WS_XT);
  u16* hbuf = (u16*)(ws + WS_H);
  u32* barr = (u32*)(ws + WS_BAR);
  float* out = (float*)d_out;

  for (int l = 0; l < 4; ++l) {
    int NC = (l == 0) ? 17 : 32;
    int din = (l == 0) ? 64 : 1024;
    bf16* dst = Wp + ((l == 0) ? 0 : (4456448 + (size_t)(l - 1) * 8388608));
    int total = 32 * NC * 128 * 64;
    pack_w<<<(total + 255) / 256, 256, 0, stream>>>(Wih[l], Whh[l], dst, NC, din);
    pack_bias<<<16, 256, 0, stream>>>(bih[l], bhh[l], biasc + l * 4096);
  }
  pack_x<<<(TLEN * BATCH * 64 + 255) / 256, 256, 0, stream>>>(x, xT);
  hipMemsetAsync(ws + WS_H, 0, 4194304u + 256u, stream);

  void* args[] = {(void*)&Wp, (void*)&biasc, (void*)&xT, (void*)&hbuf, (void*)&out, (void*)&barr};
  hipLaunchCooperativeKernel((void*)lstm_main, dim3(256), dim3(512), args, 0, stream);
}